// Round 2
// baseline (2037.775 us; speedup 1.0000x reference)
//
#include <hip/hip_runtime.h>
#include <hip/hip_bf16.h>
#include <math.h>

// Problem constants
#define BB 2
#define SS 2048
#define DD 2048
#define HH 32
#define HDD 64
#define MBB 16
#define NN 128

typedef unsigned short u16;
typedef short bf16x8_t __attribute__((ext_vector_type(8)));
typedef float f32x4_t __attribute__((ext_vector_type(4)));

__device__ __forceinline__ float b2f(u16 u) { return __uint_as_float(((unsigned)u) << 16); }
__device__ __forceinline__ u16 f2b(float f) {
    unsigned u = __float_as_uint(f);
    return (u16)((u + 0x7FFFu + ((u >> 16) & 1u)) >> 16);
}
__device__ __forceinline__ float rdl(float v, int l) {
    return __uint_as_float(__builtin_amdgcn_readlane(__float_as_uint(v), l));
}
__device__ __forceinline__ float wsum(float x) {
    x += __shfl_xor(x, 32);
    x += __shfl_xor(x, 16);
    x += __shfl_xor(x, 8);
    x += __shfl_xor(x, 4);
    x += __shfl_xor(x, 2);
    x += __shfl_xor(x, 1);
    return x;
}

typedef __attribute__((address_space(3))) unsigned int lds_u32;
typedef __attribute__((address_space(1))) const unsigned int glb_u32;
__device__ __forceinline__ void async_copy16(const void* g, void* l) {
    __builtin_amdgcn_global_load_lds((glb_u32*)g, (lds_u32*)l, 16, 0, 0);
}

// ---------------- elementwise fp32 -> bf16 ----------------
__global__ void k_cvt(const float* __restrict__ s, u16* __restrict__ d, int n) {
    int i = blockIdx.x * 256 + threadIdx.x;
    if (i < n) d[i] = f2b(s[i]);
}

// ---------------- cos/sin tables ----------------
__global__ void k_trig(const float* __restrict__ pf, float* __restrict__ ct, float* __restrict__ st) {
    int i = blockIdx.x * 256 + threadIdx.x;  // 65536 = S*32
    float f = pf[i];
    ct[i] = cosf(f);
    st[i] = sinf(f);
}

// ---------------- bf16 MFMA GEMM:  C[M,N] = A[M,K] * B[N,K]^T ----------------
// EPI 0: store fp32 row-major to Cout (M x N)
// EPI 1: store bf16 to (B,H,S,HD) layout (qkv projections)
template <int EPI>
__global__ __launch_bounds__(256) void k_gemm_bt(const u16* __restrict__ A, const u16* __restrict__ Bm,
                                                 void* __restrict__ Cout, int M, int Nn, int K) {
    __shared__ u16 As[128 * 32];
    __shared__ u16 Bs[128 * 32];
    int tid = threadIdx.x, lane = tid & 63, wv = tid >> 6;
    int m0 = blockIdx.y * 128, n0 = blockIdx.x * 128;
    int wm = wv >> 1, wn = wv & 1;

    f32x4_t acc[4][4];
    f32x4_t zero = {0.f, 0.f, 0.f, 0.f};
#pragma unroll
    for (int a = 0; a < 4; ++a)
#pragma unroll
        for (int b = 0; b < 4; ++b) acc[a][b] = zero;

    int mrow = lane & 15, qk = (lane >> 4) * 8;
    const int kTiles = K >> 5;
    for (int kt = 0; kt < kTiles; ++kt) {
        __syncthreads();
        int kb = kt << 5;
#pragma unroll
        for (int it = 0; it < 2; ++it) {
            int cb = it * 256 + wv * 64;  // wave-uniform chunk base
            int c = cb + lane;
            const u16* gpA = A + (m0 + (c >> 2)) * K + kb + ((c & 3) << 3);
            async_copy16(gpA, &As[cb << 3]);
            const u16* gpB = Bm + (n0 + (c >> 2)) * K + kb + ((c & 3) << 3);
            async_copy16(gpB, &Bs[cb << 3]);
        }
        asm volatile("s_waitcnt vmcnt(0)" ::: "memory");
        __syncthreads();

        bf16x8_t af[4], bfr[4];
#pragma unroll
        for (int mi = 0; mi < 4; ++mi)
            af[mi] = *(const bf16x8_t*)&As[(wm * 64 + mi * 16 + mrow) * 32 + qk];
#pragma unroll
        for (int ni = 0; ni < 4; ++ni)
            bfr[ni] = *(const bf16x8_t*)&Bs[(wn * 64 + ni * 16 + mrow) * 32 + qk];
#pragma unroll
        for (int mi = 0; mi < 4; ++mi)
#pragma unroll
            for (int ni = 0; ni < 4; ++ni)
                acc[mi][ni] = __builtin_amdgcn_mfma_f32_16x16x32_bf16(af[mi], bfr[ni], acc[mi][ni], 0, 0, 0);
    }

    int col16 = lane & 15, rq = (lane >> 4) * 4;
#pragma unroll
    for (int mi = 0; mi < 4; ++mi) {
#pragma unroll
        for (int ni = 0; ni < 4; ++ni) {
#pragma unroll
            for (int r = 0; r < 4; ++r) {
                int gr = m0 + wm * 64 + mi * 16 + rq + r;
                int gc = n0 + wn * 64 + ni * 16 + col16;
                float val = acc[mi][ni][r];
                if (EPI == 0) {
                    ((float*)Cout)[gr * Nn + gc] = val;
                } else {
                    int b = gr >> 11, s2 = gr & 2047, hh = gc >> 6, hd = gc & 63;
                    ((u16*)Cout)[(((b * HH + hh) * SS) + s2) * HDD + hd] = f2b(val);
                }
            }
        }
    }
}

// ---------------- RoPE, in place on bf16 (B,H,S,HD) ----------------
__global__ void k_rope(u16* __restrict__ t, const float* __restrict__ ct, const float* __restrict__ st) {
    int idx = blockIdx.x * 256 + threadIdx.x;  // B*H*S*32 = 4194304
    int i = idx & 31, s = (idx >> 5) & 2047;
    unsigned pk = ((unsigned*)t)[idx];
    float x1 = b2f((u16)(pk & 0xFFFF)), x2 = b2f((u16)(pk >> 16));
    float c = ct[s * 32 + i], sn = st[s * 32 + i];
    float y1 = x1 * c - x2 * sn;
    float y2 = x1 * sn + x2 * c;
    ((unsigned*)t)[idx] = (unsigned)f2b(y1) | (((unsigned)f2b(y2)) << 16);
}

// ---------------- ilr gate: lr[b,h,s] = sigmoid(x[b,s,:].ilr_W[h] + ilr_b[h]) / HD ----------------
__global__ __launch_bounds__(256) void k_lr(const float* __restrict__ x, const float* __restrict__ ilrW,
                                            const float* __restrict__ ilrb, float* __restrict__ lrout) {
    __shared__ float xr[2048];
    int row = blockIdx.x;  // b*S + s
    int tid = threadIdx.x, lane = tid & 63, wv = tid >> 6;
    const float* xp = x + row * 2048;
    for (int i = tid; i < 2048; i += 256) xr[i] = xp[i];
    __syncthreads();
    int b = row >> 11, s = row & 2047;
#pragma unroll
    for (int sub = 0; sub < 8; ++sub) {   // 4 waves x 8 = 32 heads (was 16: BUG fixed)
        int h = wv * 8 + sub;
        const float* wp = ilrW + h * 2048;
        float a = 0.f;
        for (int t2 = lane; t2 < 2048; t2 += 64) a += xr[t2] * wp[t2];
        a = wsum(a);
        if (lane == 0) {
            float z = a + ilrb[h];
            lrout[((b * HH + h) * SS) + s] = (1.0f / (1.0f + expf(-z))) * (1.0f / 64.0f);
        }
    }
}

// ---------------- the TTT scan: one block per (b,h), 8 waves, rows {w, 15-w} ----------------
__global__ __launch_bounds__(512) void k_scan(const u16* __restrict__ qb, const u16* __restrict__ kb2,
                                              const u16* __restrict__ vb, const float* __restrict__ lrbuf,
                                              const float* __restrict__ lgs, const float* __restrict__ tg,
                                              const float* __restrict__ tb, const float* __restrict__ W0,
                                              const float* __restrict__ b0, float* __restrict__ ys) {
    __shared__ float Wl[4096];       // W[k][d]
    __shared__ float xkl[16 * 65];   // XK rows (padded)
    __shared__ float gradl[16 * 65]; // grad rows (padded)
    __shared__ float al[1024];       // a[j][k] = gs15*lr[j]*XK[j][k]
    __shared__ float bbl[64];

    int bh = blockIdx.x, b = bh >> 5, h = bh & 31;
    int tid = threadIdx.x, lane = tid & 63, wv = tid >> 6;
    int i0 = wv, i1 = 15 - wv;

    for (int i = tid; i < 4096; i += 512) Wl[i] = W0[h * 4096 + i];
    if (tid < 64) bbl[tid] = b0[h * 64 + tid];
    float gd = tg[h * 64 + lane], bd = tb[h * 64 + lane];
    float gs0 = fmaxf(1.0f / (i0 + 1) + lgs[i0], 0.0f);
    float gs1 = fmaxf(1.0f / (i1 + 1) + lgs[i1], 0.0f);
    float gs15 = fmaxf(1.0f / 16.0f + lgs[15], 0.0f);

    const int base = bh * SS;
    // prefetch chunk 0
    int r0 = (base + i0) * 64 + lane, r1 = (base + i1) * 64 + lane;
    u16 cq0 = qb[r0], cq1 = qb[r1], ck0 = kb2[r0], ck1 = kb2[r1], cv0 = vb[r0], cv1 = vb[r1];
    float clr = lrbuf[base + (lane & 15)];
    __syncthreads();

    for (int n = 0; n < NN; ++n) {
        int s0 = n * 16;
        float xq0 = b2f(cq0), xq1 = b2f(cq1);
        float xk0 = b2f(ck0), xk1 = b2f(ck1);
        float xv0 = b2f(cv0), xv1 = b2f(cv1);
        float lrv = clr;
        float bbv = bbl[lane];

        xkl[i0 * 65 + lane] = xk0;
        xkl[i1 * 65 + lane] = xk1;
        al[i0 * 64 + lane] = gs15 * rdl(lrv, i0) * xk0;
        al[i1 * 64 + lane] = gs15 * rdl(lrv, i1) * xk1;

        // Z = XK@W + bb ; XQW = XQ@W   (vector over lane=d, scalars via readlane)
        float z0 = 0.f, z1 = 0.f, q0 = 0.f, q1 = 0.f;
#pragma unroll 8
        for (int kk = 0; kk < 64; ++kk) {
            float wr = Wl[kk * 64 + lane];
            z0 += rdl(xk0, kk) * wr;
            z1 += rdl(xk1, kk) * wr;
            q0 += rdl(xq0, kk) * wr;
            q1 += rdl(xq1, kk) * wr;
        }
        z0 += bbv;
        z1 += bbv;
        __syncthreads();  // B1: xkl, al visible

        // prefetch next chunk
        if (n + 1 < NN) {
            int p0 = (base + s0 + 16 + i0) * 64 + lane, p1 = (base + s0 + 16 + i1) * 64 + lane;
            cq0 = qb[p0]; cq1 = qb[p1];
            ck0 = kb2[p0]; ck1 = kb2[p1];
            cv0 = vb[p0]; cv1 = vb[p1];
            clr = lrbuf[base + s0 + 16 + (lane & 15)];
        }

        // grad = ln_l2_bwd(Z, XV-XK) per row
        float g0, g1;
        {
            float s1 = wsum(z0), s2 = wsum(z0 * z0);
            float mu = s1 * (1.f / 64), var = s2 * (1.f / 64) - mu * mu;
            float rstd = rsqrtf(var + 1e-5f);
            float zh = (z0 - mu) * rstd;
            float dy = gd * zh + bd - (xv0 - xk0);
            float dzh = dy * gd;
            float m1 = wsum(dzh) * (1.f / 64), m2 = wsum(dzh * zh) * (1.f / 64);
            g0 = (dzh - m1 - zh * m2) * rstd;
            gradl[i0 * 65 + lane] = g0;
        }
        {
            float s1 = wsum(z1), s2 = wsum(z1 * z1);
            float mu = s1 * (1.f / 64), var = s2 * (1.f / 64) - mu * mu;
            float rstd = rsqrtf(var + 1e-5f);
            float zh = (z1 - mu) * rstd;
            float dy = gd * zh + bd - (xv1 - xk1);
            float dzh = dy * gd;
            float m1 = wsum(dzh) * (1.f / 64), m2 = wsum(dzh * zh) * (1.f / 64);
            g1 = (dzh - m1 - zh * m2) * rstd;
            gradl[i1 * 65 + lane] = g1;
        }

        // Attn rows (tril incl diagonal), packed: lane j holds Attn[i][j]
        float ar0 = 0.f, ar1 = 0.f;
        for (int j = 0; j <= i1; ++j) {
            float xkj = xkl[j * 65 + lane];
            float p = wsum(xq1 * xkj);
            if (lane == j) ar1 = p;
            if (j <= i0) {
                float p2 = wsum(xq0 * xkj);
                if (lane == j) ar0 = p2;
            }
        }
        __syncthreads();  // B2: gradl visible

        // Z_bar[i] = XQW[i] + bb - gs[i] * sum_{j<=i} lr[j]*(1+Attn[i][j])*grad[j]
        float a0 = 0.f, a1 = 0.f, ab = 0.f;
        for (int j = 0; j <= i1; ++j) {
            float grow = gradl[j * 65 + lane];
            float lrj = rdl(lrv, j);
            a1 += lrj * (1.0f + rdl(ar1, j)) * grow;
            if (j <= i0) a0 += lrj * (1.0f + rdl(ar0, j)) * grow;
            if (wv == 0) ab += lrj * grow;  // full j=0..15 sum (i1==15 for wave 0)
        }
        float zb0 = q0 + bbv - gs0 * a0;
        float zb1 = q1 + bbv - gs1 * a1;

        // y = XQ + ln_fwd(Z_bar)
        {
            float t1 = wsum(zb0) * (1.f / 64), t2 = wsum(zb0 * zb0) * (1.f / 64);
            float vr = t2 - t1 * t1, rs = rsqrtf(vr + 1e-5f);
            float y0 = xq0 + gd * (zb0 - t1) * rs + bd;
            ys[(b * SS + s0 + i0) * DD + h * 64 + lane] = y0;
        }
        {
            float t1 = wsum(zb1) * (1.f / 64), t2 = wsum(zb1 * zb1) * (1.f / 64);
            float vr = t2 - t1 * t1, rs = rsqrtf(vr + 1e-5f);
            float y1 = xq1 + gd * (zb1 - t1) * rs + bd;
            ys[(b * SS + s0 + i1) * DD + h * 64 + lane] = y1;
        }

        // W -= (last_eta*XK)^T @ grad ; each wave owns k-rows [wv*8, wv*8+8)
        float areg[16], greg[16];
#pragma unroll
        for (int j = 0; j < 16; ++j) {
            areg[j] = al[j * 64 + lane];
            greg[j] = gradl[j * 65 + lane];
        }
#pragma unroll
        for (int kkk = 0; kkk < 8; ++kkk) {
            int krow = wv * 8 + kkk;
            float acc2 = 0.f;
#pragma unroll
            for (int j = 0; j < 16; ++j) acc2 += rdl(areg[j], krow) * greg[j];
            Wl[krow * 64 + lane] -= acc2;
        }
        if (wv == 0) bbl[lane] = bbv - gs15 * ab;
        __syncthreads();  // B3: W/bb updated
    }
}

// ---------------- post layernorm -> bf16 ----------------
__global__ __launch_bounds__(256) void k_postln(const float* __restrict__ ys, const float* __restrict__ pg,
                                                const float* __restrict__ pb, u16* __restrict__ outb) {
    __shared__ float red[8];
    int row = blockIdx.x, tid = threadIdx.x, lane = tid & 63, wv = tid >> 6;
    const float* rp = ys + row * 2048;
    float v[8];
    float s1 = 0.f, s2 = 0.f;
#pragma unroll
    for (int i = 0; i < 8; ++i) {
        v[i] = rp[tid + i * 256];
        s1 += v[i];
        s2 += v[i] * v[i];
    }
    s1 = wsum(s1);
    s2 = wsum(s2);
    if (lane == 0) {
        red[wv] = s1;
        red[wv + 4] = s2;
    }
    __syncthreads();
    float S1 = red[0] + red[1] + red[2] + red[3];
    float S2 = red[4] + red[5] + red[6] + red[7];
    float mu = S1 * (1.f / 2048), var = S2 * (1.f / 2048) - mu * mu;
    float rstd = rsqrtf(var + 1e-5f);
#pragma unroll
    for (int i = 0; i < 8; ++i) {
        int c2 = tid + i * 256;
        outb[row * 2048 + c2] = f2b(pg[c2] * (v[i] - mu) * rstd + pb[c2]);
    }
}

extern "C" void kernel_launch(void* const* d_in, const int* in_sizes, int n_in,
                              void* d_out, int out_size, void* d_ws, size_t ws_size,
                              hipStream_t stream) {
    const float* x = (const float*)d_in[0];
    const float* pf = (const float*)d_in[1];
    const float* Wq = (const float*)d_in[2];
    const float* Wk = (const float*)d_in[3];
    const float* Wv = (const float*)d_in[4];
    const float* Wo = (const float*)d_in[5];
    const float* pg = (const float*)d_in[6];
    const float* pb = (const float*)d_in[7];
    const float* ilrW = (const float*)d_in[8];
    const float* ilrb = (const float*)d_in[9];
    const float* lgs = (const float*)d_in[10];
    const float* tg = (const float*)d_in[11];
    const float* tb = (const float*)d_in[12];
    const float* W0 = (const float*)d_in[13];
    const float* b0 = (const float*)d_in[14];
    float* out = (float*)d_out;
    char* ws = (char*)d_ws;

    // workspace layout (~134 MB total)
    u16* xbf = (u16*)(ws + 0);            // 16 MB  (reused as lnb later)
    u16* wqb = (u16*)(ws + 16777216);     // 8 MB
    u16* wkb = (u16*)(ws + 25165824);     // 8 MB
    u16* wvb = (u16*)(ws + 33554432);     // 8 MB
    u16* wob = (u16*)(ws + 41943040);     // 8 MB
    u16* qbuf = (u16*)(ws + 50331648);    // 16 MB
    u16* kbuf = (u16*)(ws + 67108864);    // 16 MB
    u16* vbuf = (u16*)(ws + 83886080);    // 16 MB
    float* ct = (float*)(ws + 100663296); // 256 KB
    float* st = (float*)(ws + 100925440); // 256 KB
    float* lrb = (float*)(ws + 101187584);// 512 KB
    float* ysb = (float*)(ws + 101711872);// 32 MB
    u16* lnb = (u16*)(ws + 0);            // reuse xbf region (x_bf16 dead after QKV GEMMs)

    k_cvt<<<32768, 256, 0, stream>>>(x, xbf, 8388608);
    k_cvt<<<16384, 256, 0, stream>>>(Wq, wqb, 4194304);
    k_cvt<<<16384, 256, 0, stream>>>(Wk, wkb, 4194304);
    k_cvt<<<16384, 256, 0, stream>>>(Wv, wvb, 4194304);
    k_cvt<<<16384, 256, 0, stream>>>(Wo, wob, 4194304);
    k_trig<<<256, 256, 0, stream>>>(pf, ct, st);

    dim3 gg(16, 32);
    k_gemm_bt<1><<<gg, 256, 0, stream>>>(xbf, wqb, qbuf, 4096, 2048, 2048);
    k_gemm_bt<1><<<gg, 256, 0, stream>>>(xbf, wkb, kbuf, 4096, 2048, 2048);
    k_gemm_bt<1><<<gg, 256, 0, stream>>>(xbf, wvb, vbuf, 4096, 2048, 2048);

    k_rope<<<16384, 256, 0, stream>>>(qbuf, ct, st);
    k_rope<<<16384, 256, 0, stream>>>(kbuf, ct, st);
    k_rope<<<16384, 256, 0, stream>>>(vbuf, ct, st);

    k_lr<<<4096, 256, 0, stream>>>(x, ilrW, ilrb, lrb);

    k_scan<<<64, 512, 0, stream>>>(qbuf, kbuf, vbuf, lrb, lgs, tg, tb, W0, b0, ysb);

    k_postln<<<4096, 256, 0, stream>>>(ysb, pg, pb, lnb);
    k_gemm_bt<0><<<gg, 256, 0, stream>>>(lnb, wob, out, 4096, 2048, 2048);
}

// Round 3
// 1036.905 us; speedup vs baseline: 1.9652x; 1.9652x over previous
//
#include <hip/hip_runtime.h>
#include <hip/hip_bf16.h>
#include <math.h>

// Problem constants
#define BB 2
#define SS 2048
#define DD 2048
#define HH 32
#define HDD 64
#define MBB 16
#define NN 128

typedef unsigned short u16;
typedef short bf16x8_t __attribute__((ext_vector_type(8)));
typedef float f32x4_t __attribute__((ext_vector_type(4)));

__device__ __forceinline__ float b2f(u16 u) { return __uint_as_float(((unsigned)u) << 16); }
__device__ __forceinline__ u16 f2b(float f) {
    unsigned u = __float_as_uint(f);
    return (u16)((u + 0x7FFFu + ((u >> 16) & 1u)) >> 16);
}
__device__ __forceinline__ unsigned pk2(float a, float b) {
    return (unsigned)f2b(a) | ((unsigned)f2b(b) << 16);
}
__device__ __forceinline__ unsigned pk2r(u16 a, u16 b) { return (unsigned)a | ((unsigned)b << 16); }
__device__ __forceinline__ float wsum(float x) {
    x += __shfl_xor(x, 32);
    x += __shfl_xor(x, 16);
    x += __shfl_xor(x, 8);
    x += __shfl_xor(x, 4);
    x += __shfl_xor(x, 2);
    x += __shfl_xor(x, 1);
    return x;
}

typedef __attribute__((address_space(3))) unsigned int lds_u32;
typedef __attribute__((address_space(1))) const unsigned int glb_u32;
__device__ __forceinline__ void async_copy16(const void* g, void* l) {
    __builtin_amdgcn_global_load_lds((glb_u32*)g, (lds_u32*)l, 16, 0, 0);
}

// ---------------- elementwise fp32 -> bf16 ----------------
__global__ void k_cvt(const float* __restrict__ s, u16* __restrict__ d, int n) {
    int i = blockIdx.x * 256 + threadIdx.x;
    if (i < n) d[i] = f2b(s[i]);
}

// ---------------- cos/sin tables ----------------
__global__ void k_trig(const float* __restrict__ pf, float* __restrict__ ct, float* __restrict__ st) {
    int i = blockIdx.x * 256 + threadIdx.x;  // 65536 = S*32
    float f = pf[i];
    ct[i] = cosf(f);
    st[i] = sinf(f);
}

// ---------------- bf16 MFMA GEMM:  C[M,N] = A[M,K] * B[N,K]^T ----------------
// EPI 0: store fp32 row-major to Cout (M x N)
// EPI 1: apply RoPE, store bf16 to (B,H,S,HD) layout (qkv projections)
template <int EPI>
__global__ __launch_bounds__(256) void k_gemm_bt(const u16* __restrict__ A, const u16* __restrict__ Bm,
                                                 void* __restrict__ Cout, int M, int Nn, int K,
                                                 const float* __restrict__ ct, const float* __restrict__ st) {
    __shared__ u16 As[128 * 32];
    __shared__ u16 Bs[128 * 32];
    int tid = threadIdx.x, lane = tid & 63, wv = tid >> 6;
    int m0 = blockIdx.y * 128, n0 = blockIdx.x * 128;
    int wm = wv >> 1, wn = wv & 1;

    f32x4_t acc[4][4];
    f32x4_t zero = {0.f, 0.f, 0.f, 0.f};
#pragma unroll
    for (int a = 0; a < 4; ++a)
#pragma unroll
        for (int b = 0; b < 4; ++b) acc[a][b] = zero;

    int mrow = lane & 15, qk = (lane >> 4) * 8;
    const int kTiles = K >> 5;
    for (int kt = 0; kt < kTiles; ++kt) {
        __syncthreads();
        int kb = kt << 5;
#pragma unroll
        for (int it = 0; it < 2; ++it) {
            int cb = it * 256 + wv * 64;  // wave-uniform chunk base
            int c = cb + lane;
            const u16* gpA = A + (m0 + (c >> 2)) * K + kb + ((c & 3) << 3);
            async_copy16(gpA, &As[cb << 3]);
            const u16* gpB = Bm + (n0 + (c >> 2)) * K + kb + ((c & 3) << 3);
            async_copy16(gpB, &Bs[cb << 3]);
        }
        asm volatile("s_waitcnt vmcnt(0)" ::: "memory");
        __syncthreads();

        bf16x8_t af[4], bfr[4];
#pragma unroll
        for (int mi = 0; mi < 4; ++mi)
            af[mi] = *(const bf16x8_t*)&As[(wm * 64 + mi * 16 + mrow) * 32 + qk];
#pragma unroll
        for (int ni = 0; ni < 4; ++ni)
            bfr[ni] = *(const bf16x8_t*)&Bs[(wn * 64 + ni * 16 + mrow) * 32 + qk];
#pragma unroll
        for (int mi = 0; mi < 4; ++mi)
#pragma unroll
            for (int ni = 0; ni < 4; ++ni)
                acc[mi][ni] = __builtin_amdgcn_mfma_f32_16x16x32_bf16(af[mi], bfr[ni], acc[mi][ni], 0, 0, 0);
    }

    int col16 = lane & 15, rq = (lane >> 4) * 4;
#pragma unroll
    for (int mi = 0; mi < 4; ++mi) {
#pragma unroll
        for (int ni = 0; ni < 4; ++ni) {
#pragma unroll
            for (int r = 0; r < 4; ++r) {
                int gr = m0 + wm * 64 + mi * 16 + rq + r;
                int gc = n0 + wn * 64 + ni * 16 + col16;
                float val = acc[mi][ni][r];
                if (EPI == 0) {
                    ((float*)Cout)[gr * Nn + gc] = val;
                } else {
                    // fused RoPE: pair partner sits on lane^1 (gc differs in bit 0)
                    int b = gr >> 11, s2 = gr & 2047, hh = gc >> 6, hd = gc & 63;
                    int fi = s2 * 32 + (hd >> 1);
                    float c = ct[fi], sn = st[fi];
                    float partner = __shfl_xor(val, 1);
                    float y = (gc & 1) ? (partner * sn + val * c) : (val * c - partner * sn);
                    ((u16*)Cout)[(((b * HH + hh) * SS) + s2) * HDD + hd] = f2b(y);
                }
            }
        }
    }
}

// ---------------- ilr gate: lr[b,h,s] = sigmoid(x[b,s,:].ilr_W[h] + ilr_b[h]) / HD ----------------
__global__ __launch_bounds__(256) void k_lr(const float* __restrict__ x, const float* __restrict__ ilrW,
                                            const float* __restrict__ ilrb, float* __restrict__ lrout) {
    __shared__ float xr[2048];
    int row = blockIdx.x;  // b*S + s
    int tid = threadIdx.x, lane = tid & 63, wv = tid >> 6;
    const float* xp = x + row * 2048;
    for (int i = tid; i < 2048; i += 256) xr[i] = xp[i];
    __syncthreads();
    int b = row >> 11, s = row & 2047;
#pragma unroll
    for (int sub = 0; sub < 8; ++sub) {  // 4 waves x 8 = 32 heads
        int h = wv * 8 + sub;
        const float* wp = ilrW + h * 2048;
        float a = 0.f;
        for (int t2 = lane; t2 < 2048; t2 += 64) a += xr[t2] * wp[t2];
        a = wsum(a);
        if (lane == 0) {
            float z = a + ilrb[h];
            lrout[((b * HH + h) * SS) + s] = (1.0f / (1.0f + expf(-z))) * (1.0f / 64.0f);
        }
    }
}

// ---------------- TTT scan: ONE WAVE per (b,h), all matmuls via MFMA ----------------
// Layouts (16x16x32 bf16 MFMA, m89-verified):
//   A/B-frag: [row = lane&15][k = quad*8 + j]   (bf16x8)
//   C/D:      [row = quad*4 + reg][col = lane&15] (f32x4)
// W master: fp32 C-layout regs Wc[tm][tn] = W[d1=tm*16+quad*4+r][d2=tn*16+col]
// WbL LDS [d2][d1] bf16: B-frag source for Z/XQW. XKT/GST LDS: [d][j] transposed,
// j padded to 32 with zeros so K=16 products use one K=32 MFMA.
__global__ __launch_bounds__(64) void k_scan(const u16* __restrict__ qb, const u16* __restrict__ kb2,
                                             const u16* __restrict__ vb, const float* __restrict__ lrbuf,
                                             const float* __restrict__ lgs, const float* __restrict__ tg,
                                             const float* __restrict__ tb, const float* __restrict__ W0,
                                             const float* __restrict__ b0, float* __restrict__ ys) {
    __shared__ u16 WbL[4096];   // [d2][d1]
    __shared__ u16 XKT[2048];   // [d1][j(32)]
    __shared__ u16 GST[2048];   // [d2][j(32)]
    __shared__ float PUL[512];  // [i][j(32)]

    const int bh = blockIdx.x, h = bh & 31, b = bh >> 5;
    const int lane = threadIdx.x & 63;
    const int quad = lane >> 4, col = lane & 15;
    const int base = bh * SS;

    {  // zero-init aux LDS (upper j-halves must stay zero forever)
        unsigned* p1 = (unsigned*)XKT;
        unsigned* p2 = (unsigned*)GST;
        for (int i = lane; i < 1024; i += 64) { p1[i] = 0; p2[i] = 0; }
        for (int i = lane; i < 512; i += 64) PUL[i] = 0.f;
    }

    float gd4[4], bd4[4], bbv[4];
#pragma unroll
    for (int tn = 0; tn < 4; ++tn) {
        gd4[tn] = tg[h * 64 + tn * 16 + col];
        bd4[tn] = tb[h * 64 + tn * 16 + col];
        bbv[tn] = b0[h * 64 + tn * 16 + col];
    }
    float gs4[4];
#pragma unroll
    for (int r = 0; r < 4; ++r) {
        int i = quad * 4 + r;
        gs4[r] = fmaxf(1.f / (float)(i + 1) + lgs[i], 0.f);
    }
    const float gs15 = fmaxf(1.f / 16.f + lgs[15], 0.f);

    f32x4_t Wc[4][4];
#pragma unroll
    for (int tm = 0; tm < 4; ++tm)
#pragma unroll
        for (int tn = 0; tn < 4; ++tn)
#pragma unroll
            for (int r = 0; r < 4; ++r)
                Wc[tm][tn][r] = W0[h * 4096 + (tm * 16 + quad * 4 + r) * 64 + tn * 16 + col];

    {  // initial Wb
        unsigned* wb32 = (unsigned*)WbL;
#pragma unroll
        for (int tn = 0; tn < 4; ++tn)
#pragma unroll
            for (int tm = 0; tm < 4; ++tm) {
                int a = (tn * 16 + col) * 32 + tm * 8 + quad * 2;
                wb32[a] = pk2(Wc[tm][tn][0], Wc[tm][tn][1]);
                wb32[a + 1] = pk2(Wc[tm][tn][2], Wc[tm][tn][3]);
            }
    }

    // prefetch chunk 0: A-frags of XK/XQ + lr
    bf16x8_t ka[2], qa[2];
    float lr4[4];
    {
        const u16* kp = kb2 + (base + col) * 64;
        const u16* qp = qb + (base + col) * 64;
#pragma unroll
        for (int kh = 0; kh < 2; ++kh) {
            ka[kh] = *(const bf16x8_t*)(kp + kh * 32 + quad * 8);
            qa[kh] = *(const bf16x8_t*)(qp + kh * 32 + quad * 8);
        }
#pragma unroll
        for (int r = 0; r < 4; ++r) lr4[r] = lrbuf[base + quad * 4 + r];
    }

    const f32x4_t zf = {0.f, 0.f, 0.f, 0.f};

    for (int n = 0; n < NN; ++n) {
        const int s0 = n * 16;

        // W B-frags (written end of previous step)
        bf16x8_t wbf[4][2];
#pragma unroll
        for (int tn = 0; tn < 4; ++tn)
#pragma unroll
            for (int kh = 0; kh < 2; ++kh)
                wbf[tn][kh] = *(const bf16x8_t*)&WbL[(tn * 16 + col) * 64 + kh * 32 + quad * 8];

        // Z = XK@W, XQW = XQ@W, Attn = XQ@XK^T  (vs old W)
        f32x4_t z[4], xqw[4], attn;
#pragma unroll
        for (int tn = 0; tn < 4; ++tn) {
            z[tn] = __builtin_amdgcn_mfma_f32_16x16x32_bf16(ka[1], wbf[tn][1], zf, 0, 0, 0);
            z[tn] = __builtin_amdgcn_mfma_f32_16x16x32_bf16(ka[0], wbf[tn][0], z[tn], 0, 0, 0);
            xqw[tn] = __builtin_amdgcn_mfma_f32_16x16x32_bf16(qa[1], wbf[tn][1], zf, 0, 0, 0);
            xqw[tn] = __builtin_amdgcn_mfma_f32_16x16x32_bf16(qa[0], wbf[tn][0], xqw[tn], 0, 0, 0);
        }
        attn = __builtin_amdgcn_mfma_f32_16x16x32_bf16(qa[1], ka[1], zf, 0, 0, 0);
        attn = __builtin_amdgcn_mfma_f32_16x16x32_bf16(qa[0], ka[0], attn, 0, 0, 0);

        // C-layout scalar loads for this chunk (independent, overlap with MFMA/LN)
        u16 kraw[16], vraw[16], qraw[16];
#pragma unroll
        for (int tn = 0; tn < 4; ++tn)
#pragma unroll
            for (int r = 0; r < 4; ++r) {
                int idx = (base + s0 + quad * 4 + r) * 64 + tn * 16 + col;
                kraw[tn * 4 + r] = kb2[idx];
                vraw[tn * 4 + r] = vb[idx];
                qraw[tn * 4 + r] = qb[idx];
            }

        // prefetch next chunk A-frags + lr (clamped on last iter)
        bf16x8_t nka[2], nqa[2];
        float nlr[4];
        {
            const int sp = (n + 1 < NN) ? s0 + 16 : s0;
            const u16* kp = kb2 + (base + sp + col) * 64;
            const u16* qp = qb + (base + sp + col) * 64;
#pragma unroll
            for (int kh = 0; kh < 2; ++kh) {
                nka[kh] = *(const bf16x8_t*)(kp + kh * 32 + quad * 8);
                nqa[kh] = *(const bf16x8_t*)(qp + kh * 32 + quad * 8);
            }
#pragma unroll
            for (int r = 0; r < 4; ++r) nlr[r] = lrbuf[base + sp + quad * 4 + r];
        }

        // XK^T into LDS (raw bf16 repack, no cvt)
        {
            unsigned* x32 = (unsigned*)XKT;
#pragma unroll
            for (int tn = 0; tn < 4; ++tn) {
                int a = (tn * 16 + col) * 16 + quad * 2;
                x32[a] = pk2r(kraw[tn * 4 + 0], kraw[tn * 4 + 1]);
                x32[a + 1] = pk2r(kraw[tn * 4 + 2], kraw[tn * 4 + 3]);
            }
        }

        // Z += bb ; grad = ln_l2_bwd(Z, XV-XK)
#pragma unroll
        for (int tn = 0; tn < 4; ++tn)
#pragma unroll
            for (int r = 0; r < 4; ++r) z[tn][r] += bbv[tn];

        float mu4[4], rstd4[4], m1[4], m2[4];
#pragma unroll
        for (int r = 0; r < 4; ++r) {
            float s1 = z[0][r] + z[1][r] + z[2][r] + z[3][r];
            float s2 = z[0][r] * z[0][r] + z[1][r] * z[1][r] + z[2][r] * z[2][r] + z[3][r] * z[3][r];
#pragma unroll
            for (int m = 1; m <= 8; m <<= 1) { s1 += __shfl_xor(s1, m); s2 += __shfl_xor(s2, m); }
            float mu = s1 * (1.f / 64.f);
            float var = s2 * (1.f / 64.f) - mu * mu;
            mu4[r] = mu;
            rstd4[r] = rsqrtf(var + 1e-5f);
            m1[r] = 0.f;
            m2[r] = 0.f;
        }
#pragma unroll
        for (int tn = 0; tn < 4; ++tn)
#pragma unroll
            for (int r = 0; r < 4; ++r) {
                float zh = (z[tn][r] - mu4[r]) * rstd4[r];
                float tgt = b2f(vraw[tn * 4 + r]) - b2f(kraw[tn * 4 + r]);
                float dzh = (gd4[tn] * zh + bd4[tn] - tgt) * gd4[tn];
                m1[r] += dzh;
                m2[r] += dzh * zh;
            }
#pragma unroll
        for (int r = 0; r < 4; ++r) {
#pragma unroll
            for (int m = 1; m <= 8; m <<= 1) { m1[r] += __shfl_xor(m1[r], m); m2[r] += __shfl_xor(m2[r], m); }
            m1[r] *= (1.f / 64.f);
            m2[r] *= (1.f / 64.f);
        }
        float gS[4][4];  // lr[j] * grad[j][d]  (C-layout)
#pragma unroll
        for (int tn = 0; tn < 4; ++tn)
#pragma unroll
            for (int r = 0; r < 4; ++r) {
                float zh = (z[tn][r] - mu4[r]) * rstd4[r];
                float tgt = b2f(vraw[tn * 4 + r]) - b2f(kraw[tn * 4 + r]);
                float dzh = (gd4[tn] * zh + bd4[tn] - tgt) * gd4[tn];
                gS[tn][r] = lr4[r] * ((dzh - m1[r] - zh * m2[r]) * rstd4[r]);
            }
        {  // gradS^T into LDS
            unsigned* g32 = (unsigned*)GST;
#pragma unroll
            for (int tn = 0; tn < 4; ++tn) {
                int a = (tn * 16 + col) * 16 + quad * 2;
                g32[a] = pk2(gS[tn][0], gS[tn][1]);
                g32[a + 1] = pk2(gS[tn][2], gS[tn][3]);
            }
        }
        // Pu = tril(1 + Attn)
#pragma unroll
        for (int r = 0; r < 4; ++r) {
            float pv = (col <= quad * 4 + r) ? (1.f + attn[r]) : 0.f;
            PUL[(quad * 4 + r) * 32 + col] = pv;
        }

        // fragment reads
        bf16x8_t xkf[4], gsf[4], puf;
#pragma unroll
        for (int t = 0; t < 4; ++t) {
            xkf[t] = *(const bf16x8_t*)&XKT[(t * 16 + col) * 32 + quad * 8];
            gsf[t] = *(const bf16x8_t*)&GST[(t * 16 + col) * 32 + quad * 8];
        }
        {
            const float* pp = &PUL[col * 32 + quad * 8];
            u16* pbp = (u16*)&puf;
#pragma unroll
            for (int j = 0; j < 8; ++j) pbp[j] = f2b(pp[j]);
        }

        // Z_bar = XQW + bb - gs[i] * (Pu @ gradS)   (reuse z as zbar)
#pragma unroll
        for (int tn = 0; tn < 4; ++tn) {
            f32x4_t pg = __builtin_amdgcn_mfma_f32_16x16x32_bf16(puf, gsf[tn], zf, 0, 0, 0);
#pragma unroll
            for (int r = 0; r < 4; ++r) z[tn][r] = xqw[tn][r] + bbv[tn] - gs4[r] * pg[r];
        }
        // y = XQ + ln_fwd(Z_bar)
#pragma unroll
        for (int r = 0; r < 4; ++r) {
            float s1 = z[0][r] + z[1][r] + z[2][r] + z[3][r];
            float s2 = z[0][r] * z[0][r] + z[1][r] * z[1][r] + z[2][r] * z[2][r] + z[3][r] * z[3][r];
#pragma unroll
            for (int m = 1; m <= 8; m <<= 1) { s1 += __shfl_xor(s1, m); s2 += __shfl_xor(s2, m); }
            float mu = s1 * (1.f / 64.f);
            float var = s2 * (1.f / 64.f) - mu * mu;
            mu4[r] = mu;
            rstd4[r] = rsqrtf(var + 1e-5f);
        }
#pragma unroll
        for (int tn = 0; tn < 4; ++tn)
#pragma unroll
            for (int r = 0; r < 4; ++r) {
                float y = b2f(qraw[tn * 4 + r]) + gd4[tn] * (z[tn][r] - mu4[r]) * rstd4[r] + bd4[tn];
                ys[(b * SS + s0 + quad * 4 + r) * DD + h * 64 + tn * 16 + col] = y;
            }

        // b update: bb -= gs15 * colsum(gradS)
#pragma unroll
        for (int tn = 0; tn < 4; ++tn) {
            float c = gS[tn][0] + gS[tn][1] + gS[tn][2] + gS[tn][3];
            c += __shfl_xor(c, 16);
            c += __shfl_xor(c, 32);
            bbv[tn] -= gs15 * c;
        }

        // W update: Wc -= gs15 * (XK^T @ gradS); then refresh Wb LDS
#pragma unroll
        for (int tm = 0; tm < 4; ++tm)
#pragma unroll
            for (int tn = 0; tn < 4; ++tn) {
                f32x4_t dw = __builtin_amdgcn_mfma_f32_16x16x32_bf16(xkf[tm], gsf[tn], zf, 0, 0, 0);
#pragma unroll
                for (int r = 0; r < 4; ++r) Wc[tm][tn][r] -= gs15 * dw[r];
            }
        {
            unsigned* wb32 = (unsigned*)WbL;
#pragma unroll
            for (int tn = 0; tn < 4; ++tn)
#pragma unroll
                for (int tm = 0; tm < 4; ++tm) {
                    int a = (tn * 16 + col) * 32 + tm * 8 + quad * 2;
                    wb32[a] = pk2(Wc[tm][tn][0], Wc[tm][tn][1]);
                    wb32[a + 1] = pk2(Wc[tm][tn][2], Wc[tm][tn][3]);
                }
        }

        ka[0] = nka[0]; ka[1] = nka[1];
        qa[0] = nqa[0]; qa[1] = nqa[1];
#pragma unroll
        for (int r = 0; r < 4; ++r) lr4[r] = nlr[r];
    }
}

// ---------------- post layernorm -> bf16 ----------------
__global__ __launch_bounds__(256) void k_postln(const float* __restrict__ ys, const float* __restrict__ pg,
                                                const float* __restrict__ pb, u16* __restrict__ outb) {
    __shared__ float red[8];
    int row = blockIdx.x, tid = threadIdx.x, lane = tid & 63, wv = tid >> 6;
    const float* rp = ys + row * 2048;
    float v[8];
    float s1 = 0.f, s2 = 0.f;
#pragma unroll
    for (int i = 0; i < 8; ++i) {
        v[i] = rp[tid + i * 256];
        s1 += v[i];
        s2 += v[i] * v[i];
    }
    s1 = wsum(s1);
    s2 = wsum(s2);
    if (lane == 0) {
        red[wv] = s1;
        red[wv + 4] = s2;
    }
    __syncthreads();
    float S1 = red[0] + red[1] + red[2] + red[3];
    float S2 = red[4] + red[5] + red[6] + red[7];
    float mu = S1 * (1.f / 2048), var = S2 * (1.f / 2048) - mu * mu;
    float rstd = rsqrtf(var + 1e-5f);
#pragma unroll
    for (int i = 0; i < 8; ++i) {
        int c2 = tid + i * 256;
        outb[row * 2048 + c2] = f2b(pg[c2] * (v[i] - mu) * rstd + pb[c2]);
    }
}

extern "C" void kernel_launch(void* const* d_in, const int* in_sizes, int n_in,
                              void* d_out, int out_size, void* d_ws, size_t ws_size,
                              hipStream_t stream) {
    const float* x = (const float*)d_in[0];
    const float* pf = (const float*)d_in[1];
    const float* Wq = (const float*)d_in[2];
    const float* Wk = (const float*)d_in[3];
    const float* Wv = (const float*)d_in[4];
    const float* Wo = (const float*)d_in[5];
    const float* pg = (const float*)d_in[6];
    const float* pb = (const float*)d_in[7];
    const float* ilrW = (const float*)d_in[8];
    const float* ilrb = (const float*)d_in[9];
    const float* lgs = (const float*)d_in[10];
    const float* tg = (const float*)d_in[11];
    const float* tb = (const float*)d_in[12];
    const float* W0 = (const float*)d_in[13];
    const float* b0 = (const float*)d_in[14];
    float* out = (float*)d_out;
    char* ws = (char*)d_ws;

    // workspace layout (~134 MB total)
    u16* xbf = (u16*)(ws + 0);             // 16 MB  (reused as lnb later)
    u16* wqb = (u16*)(ws + 16777216);      // 8 MB
    u16* wkb = (u16*)(ws + 25165824);      // 8 MB
    u16* wvb = (u16*)(ws + 33554432);      // 8 MB
    u16* wob = (u16*)(ws + 41943040);      // 8 MB
    u16* qbuf = (u16*)(ws + 50331648);     // 16 MB
    u16* kbuf = (u16*)(ws + 67108864);     // 16 MB
    u16* vbuf = (u16*)(ws + 83886080);     // 16 MB
    float* ct = (float*)(ws + 100663296);  // 256 KB
    float* st = (float*)(ws + 100925440);  // 256 KB
    float* lrb = (float*)(ws + 101187584); // 512 KB
    float* ysb = (float*)(ws + 101711872); // 32 MB
    u16* lnb = (u16*)(ws + 0);             // reuse xbf region (dead after QKV GEMMs)

    k_cvt<<<32768, 256, 0, stream>>>(x, xbf, 8388608);
    k_cvt<<<16384, 256, 0, stream>>>(Wq, wqb, 4194304);
    k_cvt<<<16384, 256, 0, stream>>>(Wk, wkb, 4194304);
    k_cvt<<<16384, 256, 0, stream>>>(Wv, wvb, 4194304);
    k_cvt<<<16384, 256, 0, stream>>>(Wo, wob, 4194304);
    k_trig<<<256, 256, 0, stream>>>(pf, ct, st);

    dim3 gg(16, 32);
    k_gemm_bt<1><<<gg, 256, 0, stream>>>(xbf, wqb, qbuf, 4096, 2048, 2048, ct, st);
    k_gemm_bt<1><<<gg, 256, 0, stream>>>(xbf, wkb, kbuf, 4096, 2048, 2048, ct, st);
    k_gemm_bt<1><<<gg, 256, 0, stream>>>(xbf, wvb, vbuf, 4096, 2048, 2048, ct, st);

    k_lr<<<4096, 256, 0, stream>>>(x, ilrW, ilrb, lrb);

    k_scan<<<64, 64, 0, stream>>>(qbuf, kbuf, vbuf, lrb, lgs, tg, tb, W0, b0, ysb);

    k_postln<<<4096, 256, 0, stream>>>(ysb, pg, pb, lnb);
    k_gemm_bt<0><<<gg, 256, 0, stream>>>(lnb, wob, out, 4096, 2048, 2048, nullptr, nullptr);
}

// Round 4
// 854.906 us; speedup vs baseline: 2.3836x; 1.2129x over previous
//
#include <hip/hip_runtime.h>
#include <hip/hip_bf16.h>
#include <math.h>

// Problem constants
#define BB 2
#define SS 2048
#define DD 2048
#define HH 32
#define HDD 64
#define MBB 16
#define NN 128

typedef unsigned short u16;
typedef short bf16x8_t __attribute__((ext_vector_type(8)));
typedef float f32x4_t __attribute__((ext_vector_type(4)));

__device__ __forceinline__ float b2f(u16 u) { return __uint_as_float(((unsigned)u) << 16); }
__device__ __forceinline__ u16 f2b(float f) {
    unsigned u = __float_as_uint(f);
    return (u16)((u + 0x7FFFu + ((u >> 16) & 1u)) >> 16);
}
__device__ __forceinline__ unsigned pk2(float a, float b) {
    return (unsigned)f2b(a) | ((unsigned)f2b(b) << 16);
}
__device__ __forceinline__ unsigned pk2r(u16 a, u16 b) { return (unsigned)a | ((unsigned)b << 16); }
__device__ __forceinline__ float wsum(float x) {
    x += __shfl_xor(x, 32);
    x += __shfl_xor(x, 16);
    x += __shfl_xor(x, 8);
    x += __shfl_xor(x, 4);
    x += __shfl_xor(x, 2);
    x += __shfl_xor(x, 1);
    return x;
}

typedef __attribute__((address_space(3))) unsigned int lds_u32;
typedef __attribute__((address_space(1))) const unsigned int glb_u32;
__device__ __forceinline__ void async_copy16(const void* g, void* l) {
    __builtin_amdgcn_global_load_lds((glb_u32*)g, (lds_u32*)l, 16, 0, 0);
}

// ---------------- fused fp32 -> bf16 for x + 4 weight matrices ----------------
// grid (4096, 6): slice 0,1 = x halves; 2..5 = Wq,Wk,Wv,Wo. 4194304 elems/slice.
__global__ __launch_bounds__(256) void k_cvt5(const float* __restrict__ x, const float* __restrict__ wq,
                                              const float* __restrict__ wk, const float* __restrict__ wv,
                                              const float* __restrict__ wo, u16* __restrict__ xb,
                                              u16* __restrict__ wqb, u16* __restrict__ wkb,
                                              u16* __restrict__ wvb, u16* __restrict__ wob) {
    int sl = blockIdx.y;
    long e = (long)(blockIdx.x * 256 + threadIdx.x) * 4;
    const float* s;
    u16* d;
    if (sl == 0) { s = x; d = xb; }
    else if (sl == 1) { s = x + 4194304; d = xb + 4194304; }
    else if (sl == 2) { s = wq; d = wqb; }
    else if (sl == 3) { s = wk; d = wkb; }
    else if (sl == 4) { s = wv; d = wvb; }
    else { s = wo; d = wob; }
    float4 f = *(const float4*)(s + e);
    uint2 o;
    o.x = pk2(f.x, f.y);
    o.y = pk2(f.z, f.w);
    *(uint2*)(d + e) = o;
}

// ---------------- cos/sin tables ----------------
__global__ void k_trig(const float* __restrict__ pf, float* __restrict__ ct, float* __restrict__ st) {
    int i = blockIdx.x * 256 + threadIdx.x;  // 65536 = S*32
    float f = pf[i];
    ct[i] = cosf(f);
    st[i] = sinf(f);
}

// ---------------- bf16 MFMA GEMM:  C[M,N] = A[M,K] * B[N,K]^T ----------------
// blockIdx.z selects among up to 3 (B, C) pairs (fused QKV); pass same ptr and gridDim.z=1 otherwise.
// EPI 0: store fp32 row-major to Cout (M x N)
// EPI 1: apply RoPE, store bf16 to (B,H,S,HD) layout (qkv projections)
template <int EPI>
__global__ __launch_bounds__(256) void k_gemm_bt(const u16* __restrict__ A, const u16* __restrict__ B0,
                                                 const u16* __restrict__ B1, const u16* __restrict__ B2,
                                                 void* __restrict__ C0, void* __restrict__ C1,
                                                 void* __restrict__ C2, int M, int Nn, int K,
                                                 const float* __restrict__ ct, const float* __restrict__ st) {
    __shared__ u16 As[128 * 32];
    __shared__ u16 Bs[128 * 32];
    int z = blockIdx.z;
    const u16* Bm = (z == 0) ? B0 : (z == 1) ? B1 : B2;
    void* Cout = (z == 0) ? C0 : (z == 1) ? C1 : C2;
    int tid = threadIdx.x, lane = tid & 63, wv = tid >> 6;
    int m0 = blockIdx.y * 128, n0 = blockIdx.x * 128;
    int wm = wv >> 1, wn = wv & 1;

    f32x4_t acc[4][4];
    f32x4_t zero = {0.f, 0.f, 0.f, 0.f};
#pragma unroll
    for (int a = 0; a < 4; ++a)
#pragma unroll
        for (int b = 0; b < 4; ++b) acc[a][b] = zero;

    int mrow = lane & 15, qk = (lane >> 4) * 8;
    const int kTiles = K >> 5;
    for (int kt = 0; kt < kTiles; ++kt) {
        __syncthreads();
        int kb = kt << 5;
#pragma unroll
        for (int it = 0; it < 2; ++it) {
            int cb = it * 256 + wv * 64;  // wave-uniform chunk base
            int c = cb + lane;
            const u16* gpA = A + (m0 + (c >> 2)) * K + kb + ((c & 3) << 3);
            async_copy16(gpA, &As[cb << 3]);
            const u16* gpB = Bm + (n0 + (c >> 2)) * K + kb + ((c & 3) << 3);
            async_copy16(gpB, &Bs[cb << 3]);
        }
        asm volatile("s_waitcnt vmcnt(0)" ::: "memory");
        __syncthreads();

        bf16x8_t af[4], bfr[4];
#pragma unroll
        for (int mi = 0; mi < 4; ++mi)
            af[mi] = *(const bf16x8_t*)&As[(wm * 64 + mi * 16 + mrow) * 32 + qk];
#pragma unroll
        for (int ni = 0; ni < 4; ++ni)
            bfr[ni] = *(const bf16x8_t*)&Bs[(wn * 64 + ni * 16 + mrow) * 32 + qk];
#pragma unroll
        for (int mi = 0; mi < 4; ++mi)
#pragma unroll
            for (int ni = 0; ni < 4; ++ni)
                acc[mi][ni] = __builtin_amdgcn_mfma_f32_16x16x32_bf16(af[mi], bfr[ni], acc[mi][ni], 0, 0, 0);
    }

    int col16 = lane & 15, rq = (lane >> 4) * 4;
#pragma unroll
    for (int mi = 0; mi < 4; ++mi) {
#pragma unroll
        for (int ni = 0; ni < 4; ++ni) {
#pragma unroll
            for (int r = 0; r < 4; ++r) {
                int gr = m0 + wm * 64 + mi * 16 + rq + r;
                int gc = n0 + wn * 64 + ni * 16 + col16;
                float val = acc[mi][ni][r];
                if (EPI == 0) {
                    ((float*)Cout)[gr * Nn + gc] = val;
                } else {
                    // fused RoPE: pair partner sits on lane^1 (gc differs in bit 0)
                    int b = gr >> 11, s2 = gr & 2047, hh = gc >> 6, hd = gc & 63;
                    int fi = s2 * 32 + (hd >> 1);
                    float c = ct[fi], sn = st[fi];
                    float partner = __shfl_xor(val, 1);
                    float y = (gc & 1) ? (partner * sn + val * c) : (val * c - partner * sn);
                    ((u16*)Cout)[(((b * HH + hh) * SS) + s2) * HDD + hd] = f2b(y);
                }
            }
        }
    }
}

// ---------------- ilr gate: lr[b,h,s] = sigmoid(x[b,s,:].ilr_W[h] + ilr_b[h]) / HD ----------------
// 4 rows per block (ilr_W L2 reuse x4), bf16 x input.
__global__ __launch_bounds__(256) void k_lr(const u16* __restrict__ xb, const float* __restrict__ ilrW,
                                            const float* __restrict__ ilrb, float* __restrict__ lrout) {
    __shared__ u16 xr[4][2048];
    int row0 = blockIdx.x * 4;
    int tid = threadIdx.x, lane = tid & 63, wv = tid >> 6;
    const unsigned* src = (const unsigned*)(xb + row0 * 2048);
    unsigned* dst = (unsigned*)xr;
    for (int i = tid; i < 4096; i += 256) dst[i] = src[i];
    __syncthreads();
    int b = row0 >> 11, s0 = row0 & 2047;
#pragma unroll
    for (int sub = 0; sub < 8; ++sub) {
        int h = wv * 8 + sub;
        const float* wp = ilrW + h * 2048;
        float a0 = 0.f, a1 = 0.f, a2 = 0.f, a3 = 0.f;
        for (int i = 0; i < 16; ++i) {
            int idx = i * 128 + lane * 2;
            float2 w2 = *(const float2*)(wp + idx);
            unsigned p0 = *(const unsigned*)&xr[0][idx];
            unsigned p1 = *(const unsigned*)&xr[1][idx];
            unsigned p2 = *(const unsigned*)&xr[2][idx];
            unsigned p3 = *(const unsigned*)&xr[3][idx];
            a0 += b2f((u16)p0) * w2.x + b2f((u16)(p0 >> 16)) * w2.y;
            a1 += b2f((u16)p1) * w2.x + b2f((u16)(p1 >> 16)) * w2.y;
            a2 += b2f((u16)p2) * w2.x + b2f((u16)(p2 >> 16)) * w2.y;
            a3 += b2f((u16)p3) * w2.x + b2f((u16)(p3 >> 16)) * w2.y;
        }
        a0 = wsum(a0);
        a1 = wsum(a1);
        a2 = wsum(a2);
        a3 = wsum(a3);
        if (lane == 0) {
            float bv = ilrb[h];
            float* op = lrout + ((b * HH + h) * SS) + s0;
            op[0] = (1.0f / (1.0f + expf(-(a0 + bv)))) * (1.0f / 64.0f);
            op[1] = (1.0f / (1.0f + expf(-(a1 + bv)))) * (1.0f / 64.0f);
            op[2] = (1.0f / (1.0f + expf(-(a2 + bv)))) * (1.0f / 64.0f);
            op[3] = (1.0f / (1.0f + expf(-(a3 + bv)))) * (1.0f / 64.0f);
        }
    }
}

// ---------------- TTT scan: ONE WAVE per (b,h), all matmuls via MFMA ----------------
// Layouts (16x16x32 bf16 MFMA, m89-verified):
//   A/B-frag: [row = lane&15][k = quad*8 + j]   (bf16x8)
//   C/D:      [row = quad*4 + reg][col = lane&15] (f32x4)
// LDS strides padded for bank spread: WbL 72 u16/row (b128 reads at 8-lane/window
// floor, u32 scatter writes 2-way=free); XKT/GST/PUL 40 u16/row.
// kraw/vraw (C-layout u16 raws) prefetched one step ahead (vbuf lines are cold);
// qraw used only in the epilogue so a top-of-step load suffices.
__global__ __launch_bounds__(64) void k_scan(const u16* __restrict__ qb, const u16* __restrict__ kb2,
                                             const u16* __restrict__ vb, const float* __restrict__ lrbuf,
                                             const float* __restrict__ lgs, const float* __restrict__ tg,
                                             const float* __restrict__ tb, const float* __restrict__ W0,
                                             const float* __restrict__ b0, u16* __restrict__ ys) {
    __shared__ u16 WbL[64 * 72];  // [d2][d1]
    __shared__ u16 XKT[64 * 40];  // [d1][j(32)]  j>=16 stays 0
    __shared__ u16 GST[64 * 40];  // [d2][j(32)]  j>=16 stays 0
    __shared__ u16 PUL[16 * 40];  // [i][j(32)]   j>=16 stays 0 (bf16)

    const int bh = blockIdx.x, h = bh & 31, b = bh >> 5;
    const int lane = threadIdx.x & 63;
    const int quad = lane >> 4, col = lane & 15;
    const int base = bh * SS;

    {  // zero-init (upper j-halves must stay zero forever)
        unsigned* p1 = (unsigned*)XKT;
        unsigned* p2 = (unsigned*)GST;
        unsigned* p3 = (unsigned*)PUL;
        for (int i = lane; i < 1280; i += 64) { p1[i] = 0; p2[i] = 0; }
        for (int i = lane; i < 320; i += 64) p3[i] = 0;
    }

    float gd4[4], bd4[4], bbv[4];
#pragma unroll
    for (int tn = 0; tn < 4; ++tn) {
        gd4[tn] = tg[h * 64 + tn * 16 + col];
        bd4[tn] = tb[h * 64 + tn * 16 + col];
        bbv[tn] = b0[h * 64 + tn * 16 + col];
    }
    float gs4[4];
#pragma unroll
    for (int r = 0; r < 4; ++r) {
        int i = quad * 4 + r;
        gs4[r] = fmaxf(1.f / (float)(i + 1) + lgs[i], 0.f);
    }
    const float gs15 = fmaxf(1.f / 16.f + lgs[15], 0.f);

    f32x4_t Wc[4][4];
#pragma unroll
    for (int tm = 0; tm < 4; ++tm)
#pragma unroll
        for (int tn = 0; tn < 4; ++tn)
#pragma unroll
            for (int r = 0; r < 4; ++r)
                Wc[tm][tn][r] = W0[h * 4096 + (tm * 16 + quad * 4 + r) * 64 + tn * 16 + col];

    {  // initial Wb
        unsigned* wb32 = (unsigned*)WbL;
#pragma unroll
        for (int tn = 0; tn < 4; ++tn)
#pragma unroll
            for (int tm = 0; tm < 4; ++tm) {
                int a = (tn * 16 + col) * 36 + tm * 4 + quad;  // u32 units; row stride 36 u32
                // layout inside row: d1 = tm*16 + quad*4 + r  ->  u32 word (tm*16+quad*4)/2 = tm*8+quad*2
                a = (tn * 16 + col) * 36 + tm * 8 + quad * 2;
                wb32[a] = pk2(Wc[tm][tn][0], Wc[tm][tn][1]);
                wb32[a + 1] = pk2(Wc[tm][tn][2], Wc[tm][tn][3]);
            }
    }

    // prefetch chunk 0: A-frags of XK/XQ, lr, and C-layout kraw/vraw
    bf16x8_t ka[2], qa[2];
    float lr4[4];
    u16 kraw[16], vraw[16];
    {
        const u16* kp = kb2 + (base + col) * 64;
        const u16* qp = qb + (base + col) * 64;
#pragma unroll
        for (int kh = 0; kh < 2; ++kh) {
            ka[kh] = *(const bf16x8_t*)(kp + kh * 32 + quad * 8);
            qa[kh] = *(const bf16x8_t*)(qp + kh * 32 + quad * 8);
        }
#pragma unroll
        for (int r = 0; r < 4; ++r) lr4[r] = lrbuf[base + quad * 4 + r];
#pragma unroll
        for (int tn = 0; tn < 4; ++tn)
#pragma unroll
            for (int r = 0; r < 4; ++r) {
                int idx = (base + quad * 4 + r) * 64 + tn * 16 + col;
                kraw[tn * 4 + r] = kb2[idx];
                vraw[tn * 4 + r] = vb[idx];
            }
    }

    const f32x4_t zf = {0.f, 0.f, 0.f, 0.f};

    for (int n = 0; n < NN; ++n) {
        const int s0 = n * 16;

        // W B-frags (written end of previous step)
        bf16x8_t wbf[4][2];
#pragma unroll
        for (int tn = 0; tn < 4; ++tn)
#pragma unroll
            for (int kh = 0; kh < 2; ++kh)
                wbf[tn][kh] = *(const bf16x8_t*)&WbL[(tn * 16 + col) * 72 + kh * 32 + quad * 8];

        // Z = XK@W, XQW = XQ@W, Attn = XQ@XK^T  (vs old W)
        f32x4_t z[4], xqw[4], attn;
#pragma unroll
        for (int tn = 0; tn < 4; ++tn) {
            z[tn] = __builtin_amdgcn_mfma_f32_16x16x32_bf16(ka[1], wbf[tn][1], zf, 0, 0, 0);
            z[tn] = __builtin_amdgcn_mfma_f32_16x16x32_bf16(ka[0], wbf[tn][0], z[tn], 0, 0, 0);
            xqw[tn] = __builtin_amdgcn_mfma_f32_16x16x32_bf16(qa[1], wbf[tn][1], zf, 0, 0, 0);
            xqw[tn] = __builtin_amdgcn_mfma_f32_16x16x32_bf16(qa[0], wbf[tn][0], xqw[tn], 0, 0, 0);
        }
        attn = __builtin_amdgcn_mfma_f32_16x16x32_bf16(qa[1], ka[1], zf, 0, 0, 0);
        attn = __builtin_amdgcn_mfma_f32_16x16x32_bf16(qa[0], ka[0], attn, 0, 0, 0);

        // qraw (current step, used only in epilogue — issue now, latency covered)
        u16 qraw[16];
#pragma unroll
        for (int tn = 0; tn < 4; ++tn)
#pragma unroll
            for (int r = 0; r < 4; ++r)
                qraw[tn * 4 + r] = qb[(base + s0 + quad * 4 + r) * 64 + tn * 16 + col];

        // prefetch next chunk: A-frags, lr, kraw/vraw (clamped on last iter)
        bf16x8_t nka[2], nqa[2];
        float nlr[4];
        u16 nkraw[16], nvraw[16];
        {
            const int sp = (n + 1 < NN) ? s0 + 16 : s0;
            const u16* kp = kb2 + (base + sp + col) * 64;
            const u16* qp = qb + (base + sp + col) * 64;
#pragma unroll
            for (int kh = 0; kh < 2; ++kh) {
                nka[kh] = *(const bf16x8_t*)(kp + kh * 32 + quad * 8);
                nqa[kh] = *(const bf16x8_t*)(qp + kh * 32 + quad * 8);
            }
#pragma unroll
            for (int r = 0; r < 4; ++r) nlr[r] = lrbuf[base + sp + quad * 4 + r];
#pragma unroll
            for (int tn = 0; tn < 4; ++tn)
#pragma unroll
                for (int r = 0; r < 4; ++r) {
                    int idx = (base + sp + quad * 4 + r) * 64 + tn * 16 + col;
                    nkraw[tn * 4 + r] = kb2[idx];
                    nvraw[tn * 4 + r] = vb[idx];
                }
        }

        // XK^T into LDS (from regs prefetched last step)
        {
            unsigned* x32 = (unsigned*)XKT;
#pragma unroll
            for (int tn = 0; tn < 4; ++tn) {
                int a = (tn * 16 + col) * 20 + quad * 2;  // row stride 40 u16 = 20 u32
                x32[a] = pk2r(kraw[tn * 4 + 0], kraw[tn * 4 + 1]);
                x32[a + 1] = pk2r(kraw[tn * 4 + 2], kraw[tn * 4 + 3]);
            }
        }

        // Z += bb ; grad = ln_l2_bwd(Z, XV-XK)
#pragma unroll
        for (int tn = 0; tn < 4; ++tn)
#pragma unroll
            for (int r = 0; r < 4; ++r) z[tn][r] += bbv[tn];

        float mu4[4], rstd4[4], m1[4], m2[4];
#pragma unroll
        for (int r = 0; r < 4; ++r) {
            float s1 = z[0][r] + z[1][r] + z[2][r] + z[3][r];
            float s2 = z[0][r] * z[0][r] + z[1][r] * z[1][r] + z[2][r] * z[2][r] + z[3][r] * z[3][r];
#pragma unroll
            for (int m = 1; m <= 8; m <<= 1) { s1 += __shfl_xor(s1, m); s2 += __shfl_xor(s2, m); }
            float mu = s1 * (1.f / 64.f);
            float var = s2 * (1.f / 64.f) - mu * mu;
            mu4[r] = mu;
            rstd4[r] = rsqrtf(var + 1e-5f);
            m1[r] = 0.f;
            m2[r] = 0.f;
        }
#pragma unroll
        for (int tn = 0; tn < 4; ++tn)
#pragma unroll
            for (int r = 0; r < 4; ++r) {
                float zh = (z[tn][r] - mu4[r]) * rstd4[r];
                float tgt = b2f(vraw[tn * 4 + r]) - b2f(kraw[tn * 4 + r]);
                float dzh = (gd4[tn] * zh + bd4[tn] - tgt) * gd4[tn];
                m1[r] += dzh;
                m2[r] += dzh * zh;
            }
#pragma unroll
        for (int r = 0; r < 4; ++r) {
#pragma unroll
            for (int m = 1; m <= 8; m <<= 1) { m1[r] += __shfl_xor(m1[r], m); m2[r] += __shfl_xor(m2[r], m); }
            m1[r] *= (1.f / 64.f);
            m2[r] *= (1.f / 64.f);
        }
        float gS[4][4];  // lr[j] * grad[j][d]  (C-layout)
#pragma unroll
        for (int tn = 0; tn < 4; ++tn)
#pragma unroll
            for (int r = 0; r < 4; ++r) {
                float zh = (z[tn][r] - mu4[r]) * rstd4[r];
                float tgt = b2f(vraw[tn * 4 + r]) - b2f(kraw[tn * 4 + r]);
                float dzh = (gd4[tn] * zh + bd4[tn] - tgt) * gd4[tn];
                gS[tn][r] = lr4[r] * ((dzh - m1[r] - zh * m2[r]) * rstd4[r]);
            }
        {  // gradS^T into LDS
            unsigned* g32 = (unsigned*)GST;
#pragma unroll
            for (int tn = 0; tn < 4; ++tn) {
                int a = (tn * 16 + col) * 20 + quad * 2;
                g32[a] = pk2(gS[tn][0], gS[tn][1]);
                g32[a + 1] = pk2(gS[tn][2], gS[tn][3]);
            }
        }
        // Pu = tril(1 + Attn), stored as bf16 rows
#pragma unroll
        for (int r = 0; r < 4; ++r) {
            float pv = (col <= quad * 4 + r) ? (1.f + attn[r]) : 0.f;
            PUL[(quad * 4 + r) * 40 + col] = f2b(pv);
        }

        // fragment reads
        bf16x8_t xkf[4], gsf[4], puf;
#pragma unroll
        for (int t = 0; t < 4; ++t) {
            xkf[t] = *(const bf16x8_t*)&XKT[(t * 16 + col) * 40 + quad * 8];
            gsf[t] = *(const bf16x8_t*)&GST[(t * 16 + col) * 40 + quad * 8];
        }
        puf = *(const bf16x8_t*)&PUL[col * 40 + quad * 8];

        // W update first (so next step's wbf read has the whole epilogue to cover latency)
#pragma unroll
        for (int tm = 0; tm < 4; ++tm)
#pragma unroll
            for (int tn = 0; tn < 4; ++tn) {
                f32x4_t dw = __builtin_amdgcn_mfma_f32_16x16x32_bf16(xkf[tm], gsf[tn], zf, 0, 0, 0);
#pragma unroll
                for (int r = 0; r < 4; ++r) Wc[tm][tn][r] -= gs15 * dw[r];
            }
        {
            unsigned* wb32 = (unsigned*)WbL;
#pragma unroll
            for (int tn = 0; tn < 4; ++tn)
#pragma unroll
                for (int tm = 0; tm < 4; ++tm) {
                    int a = (tn * 16 + col) * 36 + tm * 8 + quad * 2;
                    wb32[a] = pk2(Wc[tm][tn][0], Wc[tm][tn][1]);
                    wb32[a + 1] = pk2(Wc[tm][tn][2], Wc[tm][tn][3]);
                }
        }

        // Z_bar = XQW + bb - gs[i] * (Pu @ gradS)   (reuse z as zbar)
#pragma unroll
        for (int tn = 0; tn < 4; ++tn) {
            f32x4_t pg = __builtin_amdgcn_mfma_f32_16x16x32_bf16(puf, gsf[tn], zf, 0, 0, 0);
#pragma unroll
            for (int r = 0; r < 4; ++r) z[tn][r] = xqw[tn][r] + bbv[tn] - gs4[r] * pg[r];
        }
        // y = XQ + ln_fwd(Z_bar)  -> bf16
#pragma unroll
        for (int r = 0; r < 4; ++r) {
            float s1 = z[0][r] + z[1][r] + z[2][r] + z[3][r];
            float s2 = z[0][r] * z[0][r] + z[1][r] * z[1][r] + z[2][r] * z[2][r] + z[3][r] * z[3][r];
#pragma unroll
            for (int m = 1; m <= 8; m <<= 1) { s1 += __shfl_xor(s1, m); s2 += __shfl_xor(s2, m); }
            float mu = s1 * (1.f / 64.f);
            float var = s2 * (1.f / 64.f) - mu * mu;
            mu4[r] = mu;
            rstd4[r] = rsqrtf(var + 1e-5f);
        }
#pragma unroll
        for (int tn = 0; tn < 4; ++tn)
#pragma unroll
            for (int r = 0; r < 4; ++r) {
                float y = b2f(qraw[tn * 4 + r]) + gd4[tn] * (z[tn][r] - mu4[r]) * rstd4[r] + bd4[tn];
                ys[(b * SS + s0 + quad * 4 + r) * DD + h * 64 + tn * 16 + col] = f2b(y);
            }

        // b update: bb -= gs15 * colsum(gradS)
#pragma unroll
        for (int tn = 0; tn < 4; ++tn) {
            float c = gS[tn][0] + gS[tn][1] + gS[tn][2] + gS[tn][3];
            c += __shfl_xor(c, 16);
            c += __shfl_xor(c, 32);
            bbv[tn] -= gs15 * c;
        }

        ka[0] = nka[0]; ka[1] = nka[1];
        qa[0] = nqa[0]; qa[1] = nqa[1];
#pragma unroll
        for (int r = 0; r < 4; ++r) lr4[r] = nlr[r];
#pragma unroll
        for (int j = 0; j < 16; ++j) { kraw[j] = nkraw[j]; vraw[j] = nvraw[j]; }
    }
}

// ---------------- post layernorm (bf16 in) -> bf16 out ----------------
__global__ __launch_bounds__(256) void k_postln(const u16* __restrict__ ys, const float* __restrict__ pg,
                                                const float* __restrict__ pb, u16* __restrict__ outb) {
    __shared__ float red[8];
    int row = blockIdx.x, tid = threadIdx.x, lane = tid & 63, wv = tid >> 6;
    const u16* rp = ys + row * 2048 + tid * 8;
    uint4 pkd = *(const uint4*)rp;
    float v[8];
    v[0] = b2f((u16)pkd.x); v[1] = b2f((u16)(pkd.x >> 16));
    v[2] = b2f((u16)pkd.y); v[3] = b2f((u16)(pkd.y >> 16));
    v[4] = b2f((u16)pkd.z); v[5] = b2f((u16)(pkd.z >> 16));
    v[6] = b2f((u16)pkd.w); v[7] = b2f((u16)(pkd.w >> 16));
    float s1 = 0.f, s2 = 0.f;
#pragma unroll
    for (int i = 0; i < 8; ++i) { s1 += v[i]; s2 += v[i] * v[i]; }
    s1 = wsum(s1);
    s2 = wsum(s2);
    if (lane == 0) {
        red[wv] = s1;
        red[wv + 4] = s2;
    }
    __syncthreads();
    float S1 = red[0] + red[1] + red[2] + red[3];
    float S2 = red[4] + red[5] + red[6] + red[7];
    float mu = S1 * (1.f / 2048), var = S2 * (1.f / 2048) - mu * mu;
    float rstd = rsqrtf(var + 1e-5f);
    const float4 g0 = *(const float4*)(pg + tid * 8);
    const float4 g1 = *(const float4*)(pg + tid * 8 + 4);
    const float4 b0v = *(const float4*)(pb + tid * 8);
    const float4 b1v = *(const float4*)(pb + tid * 8 + 4);
    float o[8];
    o[0] = g0.x * (v[0] - mu) * rstd + b0v.x;
    o[1] = g0.y * (v[1] - mu) * rstd + b0v.y;
    o[2] = g0.z * (v[2] - mu) * rstd + b0v.z;
    o[3] = g0.w * (v[3] - mu) * rstd + b0v.w;
    o[4] = g1.x * (v[4] - mu) * rstd + b1v.x;
    o[5] = g1.y * (v[5] - mu) * rstd + b1v.y;
    o[6] = g1.z * (v[6] - mu) * rstd + b1v.z;
    o[7] = g1.w * (v[7] - mu) * rstd + b1v.w;
    uint4 po;
    po.x = pk2(o[0], o[1]);
    po.y = pk2(o[2], o[3]);
    po.z = pk2(o[4], o[5]);
    po.w = pk2(o[6], o[7]);
    *(uint4*)(outb + row * 2048 + tid * 8) = po;
}

extern "C" void kernel_launch(void* const* d_in, const int* in_sizes, int n_in,
                              void* d_out, int out_size, void* d_ws, size_t ws_size,
                              hipStream_t stream) {
    const float* x = (const float*)d_in[0];
    const float* pf = (const float*)d_in[1];
    const float* Wq = (const float*)d_in[2];
    const float* Wk = (const float*)d_in[3];
    const float* Wv = (const float*)d_in[4];
    const float* Wo = (const float*)d_in[5];
    const float* pg = (const float*)d_in[6];
    const float* pb = (const float*)d_in[7];
    const float* ilrW = (const float*)d_in[8];
    const float* ilrb = (const float*)d_in[9];
    const float* lgs = (const float*)d_in[10];
    const float* tg = (const float*)d_in[11];
    const float* tb = (const float*)d_in[12];
    const float* W0 = (const float*)d_in[13];
    const float* b0 = (const float*)d_in[14];
    float* out = (float*)d_out;
    char* ws = (char*)d_ws;

    // workspace layout
    u16* xbf = (u16*)(ws + 0);             // 16 MB  (reused as lnb later)
    u16* wqb = (u16*)(ws + 16777216);      // 8 MB
    u16* wkb = (u16*)(ws + 25165824);      // 8 MB
    u16* wvb = (u16*)(ws + 33554432);      // 8 MB
    u16* wob = (u16*)(ws + 41943040);      // 8 MB
    u16* qbuf = (u16*)(ws + 50331648);     // 16 MB
    u16* kbuf = (u16*)(ws + 67108864);     // 16 MB
    u16* vbuf = (u16*)(ws + 83886080);     // 16 MB
    float* ct = (float*)(ws + 100663296);  // 256 KB
    float* st = (float*)(ws + 100925440);  // 256 KB
    float* lrb = (float*)(ws + 101187584); // 512 KB
    u16* ysb = (u16*)(ws + 101711872);     // 16 MB (bf16 now)
    u16* lnb = (u16*)(ws + 0);             // reuse xbf region (dead after QKV GEMMs)

    k_cvt5<<<dim3(4096, 6), 256, 0, stream>>>(x, Wq, Wk, Wv, Wo, xbf, wqb, wkb, wvb, wob);
    k_trig<<<256, 256, 0, stream>>>(pf, ct, st);

    k_gemm_bt<1><<<dim3(16, 32, 3), 256, 0, stream>>>(xbf, wqb, wkb, wvb, qbuf, kbuf, vbuf,
                                                      4096, 2048, 2048, ct, st);

    k_lr<<<1024, 256, 0, stream>>>(xbf, ilrW, ilrb, lrb);

    k_scan<<<64, 64, 0, stream>>>(qbuf, kbuf, vbuf, lrb, lgs, tg, tb, W0, b0, ysb);

    k_postln<<<4096, 256, 0, stream>>>(ysb, pg, pb, lnb);
    k_gemm_bt<0><<<dim3(16, 32, 1), 256, 0, stream>>>(lnb, wob, wob, wob, out, out, out,
                                                      4096, 2048, 2048, nullptr, nullptr);
}